// Round 2
// baseline (366.769 us; speedup 1.0000x reference)
//
#include <hip/hip_runtime.h>
#include <hip/hip_bf16.h>

#define B_  8
#define S_  2048
#define D_  1024
#define H_  8
#define HD_ 128
#define P_  32
#define BS_ (B_*S_)
#define PI_F 3.14159265358979323846f

typedef unsigned short u16;
typedef __attribute__((ext_vector_type(4))) float  f32x4;
typedef __attribute__((ext_vector_type(8))) __bf16 bf16x8;
typedef __attribute__((ext_vector_type(8))) unsigned short u16x8;

__device__ __forceinline__ u16 f2b(float f) {
  __hip_bfloat16 h = __float2bfloat16(f);
  return __builtin_bit_cast(u16, h);
}
__device__ __forceinline__ float b2f(u16 b) {
  return __bfloat162float(__builtin_bit_cast(__hip_bfloat16, b));
}

__device__ __forceinline__ void gload_lds16(const void* g, void* l) {
  auto gp = (const __attribute__((address_space(1))) unsigned int*)g;
  auto lp = (__attribute__((address_space(3))) unsigned int*)l;
  __builtin_amdgcn_global_load_lds(gp, lp, 16, 0, 0);
}

// ---------------- x -> bf16, fused per-batch column sums ----------------
__global__ __launch_bounds__(256) void cvt_x_kernel(const float* __restrict__ x,
                                                    u16* __restrict__ xb,
                                                    float* __restrict__ xsum) {
  const int r0 = blockIdx.x * 32;           // 512 blocks, 32 rows each
  const int b = r0 >> 11;
  const int c = threadIdx.x * 4;
  float s0 = 0.f, s1 = 0.f, s2 = 0.f, s3 = 0.f;
#pragma unroll 4
  for (int i = 0; i < 32; ++i) {
    const float4 v = *reinterpret_cast<const float4*>(x + (size_t)(r0 + i) * D_ + c);
    ushort4 o;
    o.x = f2b(v.x); o.y = f2b(v.y); o.z = f2b(v.z); o.w = f2b(v.w);
    *reinterpret_cast<ushort4*>(xb + (size_t)(r0 + i) * D_ + c) = o;
    s0 += v.x; s1 += v.y; s2 += v.z; s3 += v.w;
  }
  atomicAdd(&xsum[b * D_ + c + 0], s0);
  atomicAdd(&xsum[b * D_ + c + 1], s1);
  atomicAdd(&xsum[b * D_ + c + 2], s2);
  atomicAdd(&xsum[b * D_ + c + 3], s3);
}

// ---------------- weights -> bf16 (fold cos(pi*f) into W_proj) ----------------
__global__ __launch_bounds__(256) void cvt_w_kernel(const float* __restrict__ Wproj,
                                                    const float* __restrict__ freqs,
                                                    const float* __restrict__ Wo,
                                                    u16* __restrict__ Wt1,
                                                    u16* __restrict__ Wob) {
  int i = blockIdx.x * blockDim.x + threadIdx.x;
  const int total = D_ * D_;
  for (; i < total; i += gridDim.x * blockDim.x) {
    int n = i >> 10;
    float c = cosf(PI_F * freqs[n]);
    Wt1[i] = f2b(Wproj[i] * c);
    Wob[i] = f2b(Wo[i]);
  }
}

// ---------------- bf16 GEMM  C(MxN) = A(MxK) * B(NxK)^T, bf16 out ----------------
// 256x256 tile, BK=32, 8 waves (2Mx4N), double-buffered LDS, 2-phase pipeline,
// XOR-swizzled LDS (both-sides: pre-swizzled global source + swizzled ds_read).
__global__ __launch_bounds__(512, 2) void gemm256(const u16* __restrict__ A,
                                                  const u16* __restrict__ Bm,
                                                  u16* __restrict__ C,
                                                  int M, int N, int K) {
  __shared__ __align__(16) u16 lds[32768];        // 64 KB: As[2][8192] | Bs[2][8192]
  const int tid = threadIdx.x;
  const int l = tid & 63, wid = tid >> 6;
  const int wm = wid >> 2, wn = wid & 3;          // 2 x 4 wave grid
  const int bm0 = blockIdx.x * 256, bn0 = blockIdx.y * 256;

  // staging: granule g (16B) at LDS byte g*16 holds (row=g>>2, chunk=(g&3)^((g>>3)&3))
  const int gr = tid >> 2;
  const int gc = (tid & 3) ^ ((tid >> 3) & 3);
  const u16* pA1 = A  + (size_t)(bm0 + gr)       * K + gc * 8;
  const u16* pA2 = A  + (size_t)(bm0 + gr + 128) * K + gc * 8;
  const u16* pB1 = Bm + (size_t)(bn0 + gr)       * K + gc * 8;
  const u16* pB2 = Bm + (size_t)(bn0 + gr + 128) * K + gc * 8;

  const int lr = l & 15;
  const int cs = (l >> 4) ^ ((lr >> 1) & 3);      // swizzled k-chunk for reads

  f32x4 acc[8][4] = {};

  auto stage = [&](int buf) {
    u16* da = lds + buf * 8192;
    u16* db = lds + 16384 + buf * 8192;
    gload_lds16(pA1, da + tid * 8);
    gload_lds16(pA2, da + (512 + tid) * 8);
    gload_lds16(pB1, db + tid * 8);
    gload_lds16(pB2, db + (512 + tid) * 8);
    pA1 += 32; pA2 += 32; pB1 += 32; pB2 += 32;
  };

  auto compute = [&](int buf) {
    const u16* Ab = lds + buf * 8192;
    const u16* Bb = lds + 16384 + buf * 8192;
    bf16x8 af[8], bfr[4];
#pragma unroll
    for (int m = 0; m < 8; ++m)
      af[m] = *reinterpret_cast<const bf16x8*>(Ab + (wm * 128 + m * 16 + lr) * 32 + cs * 8);
#pragma unroll
    for (int n = 0; n < 4; ++n)
      bfr[n] = *reinterpret_cast<const bf16x8*>(Bb + (wn * 64 + n * 16 + lr) * 32 + cs * 8);
#pragma unroll
    for (int m = 0; m < 8; ++m)
#pragma unroll
      for (int n = 0; n < 4; ++n)
        acc[m][n] = __builtin_amdgcn_mfma_f32_16x16x32_bf16(af[m], bfr[n], acc[m][n], 0, 0, 0);
  };

  stage(0);
  __syncthreads();
  int cur = 0;
  const int NT = K / 32;
  for (int t = 0; t < NT - 1; ++t) {
    stage(cur ^ 1);          // issue next-tile loads (overlap with compute)
    compute(cur);
    __syncthreads();         // compiler drains vmcnt before barrier -> next buf ready
    cur ^= 1;
  }
  compute(cur);

  // ---- epilogue: LDS-staged coalesced bf16 C writes, two 128-row halves ----
  const int jr = (l >> 4) * 4;
#pragma unroll
  for (int h = 0; h < 2; ++h) {
    __syncthreads();
    if (wm == h) {
#pragma unroll
      for (int m = 0; m < 8; ++m)
#pragma unroll
        for (int n = 0; n < 4; ++n)
#pragma unroll
          for (int j = 0; j < 4; ++j)
            lds[(m * 16 + jr + j) * 256 + wn * 64 + n * 16 + lr] = f2b(acc[m][n][j]);
    }
    __syncthreads();
#pragma unroll
    for (int i = 0; i < 8; ++i) {
      int g = tid + i * 512;                       // 4096 granules of 16B
      int r = g >> 5, cg = g & 31;
      *reinterpret_cast<u16x8*>(C + (size_t)(bm0 + h * 128 + r) * N + bn0 + cg * 8) =
          *reinterpret_cast<const u16x8*>(lds + g * 8);
    }
  }
}

// ---------------- coef: hm = (xsum/S) @ Wt1^T, then pm/normalize/dp/MLP ----------------
__global__ __launch_bounds__(256) void coef_kernel(const float* __restrict__ xsum,
                                                   const u16* __restrict__ Wt1,
                                                   const float* __restrict__ Wp,
                                                   const float* __restrict__ bp,
                                                   const float* __restrict__ w1,
                                                   const float* __restrict__ b1,
                                                   const float* __restrict__ w2,
                                                   const float* __restrict__ b2,
                                                   float* __restrict__ coef) {
  __shared__ float xm_s[D_];
  __shared__ float hm_s[D_];
  __shared__ float pm_s[H_ * P_];
  const int b = blockIdx.x, t = threadIdx.x;
#pragma unroll
  for (int q = 0; q < 4; ++q)
    xm_s[t * 4 + q] = xsum[b * D_ + t * 4 + q] * (1.0f / S_);
  __syncthreads();
#pragma unroll
  for (int q = 0; q < 4; ++q) {
    const int d = t * 4 + q;
    const u16* wr = Wt1 + (size_t)d * D_;
    float s = 0.f;
    for (int e = 0; e < D_; e += 8) {
      u16x8 wv = *reinterpret_cast<const u16x8*>(wr + e);
#pragma unroll
      for (int k = 0; k < 8; ++k) s += xm_s[e + k] * b2f(wv[k]);
    }
    hm_s[d] = s;
  }
  __syncthreads();
  {
    const int h = t >> 5, p = t & 31;
    float a = bp[h * P_ + p];
    const float* wp = Wp + (size_t)(h * P_ + p) * HD_;
#pragma unroll 4
    for (int e = 0; e < HD_; ++e) a += hm_s[h * HD_ + e] * wp[e];
    pm_s[t] = tanhf(a);
  }
  __syncthreads();
  if (t < 8) {
    float ss = 0.f;
    for (int p = 0; p < P_; ++p) { float v = pm_s[t * P_ + p]; ss += v * v; }
    float inv = 1.0f / fmaxf(sqrtf(ss), 1e-12f);
    for (int p = 0; p < P_; ++p) pm_s[t * P_ + p] *= inv;
  }
  __syncthreads();
  if (t < 64) {
    const int i = t >> 3, j = t & 7;
    float dp = 0.f;
    for (int p = 0; p < P_; ++p)
      dp += pm_s[i * P_ + p] * pm_s[j * P_ + p];
    float acc = b2[0];
#pragma unroll
    for (int k = 0; k < 16; ++k) {
      float z = dp * w1[k] + b1[k];
      float g = 0.5f * z * (1.0f + erff(z * 0.70710678118654752f));
      acc += g * w2[k];
    }
    float sp = (acc > 20.f) ? acc : log1pf(expf(acc));
    coef[b * 64 + t] = (i == j) ? 0.f : 0.1f / (1.0f + sp);
  }
}

// ---------------- head mixing: mixed = heads + scale(s) * coef x heads ----------------
__global__ __launch_bounds__(256) void mix_kernel(const u16* __restrict__ heads,
                                                  const float* __restrict__ coef,
                                                  u16* __restrict__ mixed) {
  __shared__ float row[D_];
  __shared__ float cf[64];
  const int r = blockIdx.x;
  const int b = r >> 11, s = r & 2047;
  const int t = threadIdx.x;
  if (t < 64) cf[t] = coef[b * 64 + t];
  const u16* hp = heads + (size_t)r * D_;
  ushort4 hv = reinterpret_cast<const ushort4*>(hp)[t];
#pragma unroll
  for (int q = 0; q < 4; ++q) row[t * 4 + q] = b2f(((u16*)&hv)[q]);
  __syncthreads();
  const float scale = (float)(s + 1) * (1.0f / S_);
  const int d0 = t * 4;
  const int h = d0 >> 7;
  float ch[8];
#pragma unroll
  for (int j = 0; j < 8; ++j) ch[j] = cf[h * 8 + j];
  ushort4 o;
#pragma unroll
  for (int q = 0; q < 4; ++q) {
    int d = d0 + q, e = d & 127;
    float tr = 0.f;
#pragma unroll
    for (int j = 0; j < 8; ++j) tr += ch[j] * row[j * 128 + e];
    ((u16*)&o)[q] = f2b(row[d] + scale * tr);
  }
  reinterpret_cast<ushort4*>(mixed + (size_t)r * D_)[t] = o;
}

// ---------------- bias + residual + LayerNorm ----------------
__global__ __launch_bounds__(256) void ln_kernel(const u16* __restrict__ ypre,
                                                 const float* __restrict__ x,
                                                 const float* __restrict__ bo,
                                                 const float* __restrict__ g,
                                                 const float* __restrict__ be,
                                                 float* __restrict__ out) {
  const int r = blockIdx.x, t = threadIdx.x;
  const u16* yp = ypre + (size_t)r * D_;
  const float* xp = x + (size_t)r * D_;
  const int d0 = t * 4;
  float4 xv = reinterpret_cast<const float4*>(xp)[t];
  ushort4 yv = reinterpret_cast<const ushort4*>(yp)[t];
  float v[4];
  float s = 0.f, ss = 0.f;
#pragma unroll
  for (int q = 0; q < 4; ++q) {
    float y = b2f(((u16*)&yv)[q]) + bo[d0 + q] + ((const float*)&xv)[q];
    v[q] = y; s += y; ss += y * y;
  }
#pragma unroll
  for (int off = 32; off; off >>= 1) {
    s += __shfl_xor(s, off);
    ss += __shfl_xor(ss, off);
  }
  __shared__ float rs[4], rss[4];
  int w = t >> 6;
  if ((t & 63) == 0) { rs[w] = s; rss[w] = ss; }
  __syncthreads();
  s = rs[0] + rs[1] + rs[2] + rs[3];
  ss = rss[0] + rss[1] + rss[2] + rss[3];
  float mu = s * (1.0f / D_);
  float var = ss * (1.0f / D_) - mu * mu;
  float rstd = rsqrtf(var + 1e-5f);
  float4 ov;
#pragma unroll
  for (int q = 0; q < 4; ++q)
    ((float*)&ov)[q] = (v[q] - mu) * rstd * g[d0 + q] + be[d0 + q];
  reinterpret_cast<float4*>(out + (size_t)r * D_)[t] = ov;
}

extern "C" void kernel_launch(void* const* d_in, const int* in_sizes, int n_in,
                              void* d_out, int out_size, void* d_ws, size_t ws_size,
                              hipStream_t stream) {
  (void)in_sizes; (void)n_in; (void)out_size; (void)ws_size;
  const float* x     = (const float*)d_in[0];
  const float* Wproj = (const float*)d_in[1];
  const float* freqs = (const float*)d_in[2];
  const float* Wp    = (const float*)d_in[3];
  const float* bp    = (const float*)d_in[4];
  const float* w1    = (const float*)d_in[5];
  const float* b1    = (const float*)d_in[6];
  const float* w2    = (const float*)d_in[7];
  const float* b2    = (const float*)d_in[8];
  const float* Wo    = (const float*)d_in[9];
  const float* bo    = (const float*)d_in[10];
  const float* ln_g  = (const float*)d_in[11];
  const float* ln_b  = (const float*)d_in[12];
  float* out = (float*)d_out;

  char* ws = (char*)d_ws;
  u16*   xbf   = (u16*)ws;                         // 33.55 MB ; later: mixed
  u16*   heads = (u16*)(ws + 33554432);            // 33.55 MB ; later: y_pre (bf16)
  u16*   Wt1   = (u16*)(ws + 67108864);            // 2 MB
  u16*   Wob   = (u16*)(ws + 69206016);            // 2 MB
  float* xsum  = (float*)(ws + 71303168);          // 32 KB
  float* coef  = (float*)(ws + 71335936);          // 2 KB

  hipMemsetAsync(xsum, 0, B_ * D_ * sizeof(float), stream);

  cvt_x_kernel<<<512, 256, 0, stream>>>(x, xbf, xsum);
  cvt_w_kernel<<<1024, 256, 0, stream>>>(Wproj, freqs, Wo, Wt1, Wob);

  dim3 g1(BS_ / 256, D_ / 256);   // (64, 4) = 256 blocks, 1/CU
  gemm256<<<g1, 512, 0, stream>>>(xbf, Wt1, heads, BS_, D_, D_);

  coef_kernel<<<8, 256, 0, stream>>>(xsum, Wt1, Wp, bp, w1, b1, w2, b2, coef);
  mix_kernel<<<BS_, 256, 0, stream>>>(heads, coef, xbf /* mixed (aliases xbf) */);

  gemm256<<<g1, 512, 0, stream>>>(xbf, Wob, heads /* y_pre (aliases heads) */, BS_, D_, D_);

  ln_kernel<<<BS_, 256, 0, stream>>>(heads, x, bo, ln_g, ln_b, out);
}

// Round 3
// 270.275 us; speedup vs baseline: 1.3570x; 1.3570x over previous
//
#include <hip/hip_runtime.h>
#include <hip/hip_bf16.h>

#define B_  8
#define S_  2048
#define D_  1024
#define H_  8
#define HD_ 128
#define P_  32
#define BS_ (B_*S_)
#define PI_F 3.14159265358979323846f

typedef unsigned short u16;
typedef __attribute__((ext_vector_type(4))) float  f32x4;
typedef __attribute__((ext_vector_type(8))) __bf16 bf16x8;
typedef __attribute__((ext_vector_type(8))) unsigned short u16x8;

__device__ __forceinline__ u16 f2b(float f) {
  __hip_bfloat16 h = __float2bfloat16(f);
  return __builtin_bit_cast(u16, h);
}
__device__ __forceinline__ float b2f(u16 b) {
  return __bfloat162float(__builtin_bit_cast(__hip_bfloat16, b));
}

__device__ __forceinline__ void gload_lds16(const void* g, void* l) {
  auto gp = (const __attribute__((address_space(1))) unsigned int*)g;
  auto lp = (__attribute__((address_space(3))) unsigned int*)l;
  __builtin_amdgcn_global_load_lds(gp, lp, 16, 0, 0);
}

// ---------------- x -> bf16, fused per-batch column sums ----------------
__global__ __launch_bounds__(256) void cvt_x_kernel(const float* __restrict__ x,
                                                    u16* __restrict__ xb,
                                                    float* __restrict__ xsum) {
  const int r0 = blockIdx.x * 32;           // 512 blocks, 32 rows each
  const int b = r0 >> 11;
  const int c = threadIdx.x * 4;
  float s0 = 0.f, s1 = 0.f, s2 = 0.f, s3 = 0.f;
#pragma unroll 4
  for (int i = 0; i < 32; ++i) {
    const float4 v = *reinterpret_cast<const float4*>(x + (size_t)(r0 + i) * D_ + c);
    ushort4 o;
    o.x = f2b(v.x); o.y = f2b(v.y); o.z = f2b(v.z); o.w = f2b(v.w);
    *reinterpret_cast<ushort4*>(xb + (size_t)(r0 + i) * D_ + c) = o;
    s0 += v.x; s1 += v.y; s2 += v.z; s3 += v.w;
  }
  atomicAdd(&xsum[b * D_ + c + 0], s0);
  atomicAdd(&xsum[b * D_ + c + 1], s1);
  atomicAdd(&xsum[b * D_ + c + 2], s2);
  atomicAdd(&xsum[b * D_ + c + 3], s3);
}

// ---------------- weights -> bf16 (fold cos(pi*f) into W_proj) ----------------
__global__ __launch_bounds__(256) void cvt_w_kernel(const float* __restrict__ Wproj,
                                                    const float* __restrict__ freqs,
                                                    const float* __restrict__ Wo,
                                                    u16* __restrict__ Wt1,
                                                    u16* __restrict__ Wob) {
  int i = blockIdx.x * blockDim.x + threadIdx.x;
  const int total = D_ * D_;
  for (; i < total; i += gridDim.x * blockDim.x) {
    int n = i >> 10;
    float c = cosf(PI_F * freqs[n]);
    Wt1[i] = f2b(Wproj[i] * c);
    Wob[i] = f2b(Wo[i]);
  }
}

// ---------------- bf16 GEMM  C(MxN) = A(MxK) * B(NxK)^T, bf16 out ----------------
// 256x256 tile, BK=32, 8 waves (2Mx4N), double-buffered LDS, 2-phase pipeline,
// XOR-swizzled LDS (both-sides: pre-swizzled global source + swizzled ds_read).
__global__ __launch_bounds__(512, 2) void gemm256(const u16* __restrict__ A,
                                                  const u16* __restrict__ Bm,
                                                  u16* __restrict__ C,
                                                  int M, int N, int K) {
  __shared__ __align__(16) u16 lds[32768];        // 64 KB: As[2][8192] | Bs[2][8192]
  const int tid = threadIdx.x;
  const int l = tid & 63, wid = tid >> 6;
  const int wm = wid >> 2, wn = wid & 3;          // 2 x 4 wave grid
  const int bm0 = blockIdx.x * 256, bn0 = blockIdx.y * 256;

  // staging: granule g (16B) at LDS byte g*16 holds (row=g>>2, chunk=(g&3)^((g>>3)&3))
  const int gr = tid >> 2;
  const int gc = (tid & 3) ^ ((tid >> 3) & 3);
  const u16* pA1 = A  + (size_t)(bm0 + gr)       * K + gc * 8;
  const u16* pA2 = A  + (size_t)(bm0 + gr + 128) * K + gc * 8;
  const u16* pB1 = Bm + (size_t)(bn0 + gr)       * K + gc * 8;
  const u16* pB2 = Bm + (size_t)(bn0 + gr + 128) * K + gc * 8;

  const int lr = l & 15;
  const int cs = (l >> 4) ^ ((lr >> 1) & 3);      // swizzled k-chunk for reads

  f32x4 acc[8][4] = {};

  auto stage = [&](int buf) {
    u16* da = lds + buf * 8192;
    u16* db = lds + 16384 + buf * 8192;
    gload_lds16(pA1, da + tid * 8);
    gload_lds16(pA2, da + (512 + tid) * 8);
    gload_lds16(pB1, db + tid * 8);
    gload_lds16(pB2, db + (512 + tid) * 8);
    pA1 += 32; pA2 += 32; pB1 += 32; pB2 += 32;
  };

  auto compute = [&](int buf) {
    const u16* Ab = lds + buf * 8192;
    const u16* Bb = lds + 16384 + buf * 8192;
    bf16x8 af[8], bfr[4];
#pragma unroll
    for (int m = 0; m < 8; ++m)
      af[m] = *reinterpret_cast<const bf16x8*>(Ab + (wm * 128 + m * 16 + lr) * 32 + cs * 8);
#pragma unroll
    for (int n = 0; n < 4; ++n)
      bfr[n] = *reinterpret_cast<const bf16x8*>(Bb + (wn * 64 + n * 16 + lr) * 32 + cs * 8);
#pragma unroll
    for (int m = 0; m < 8; ++m)
#pragma unroll
      for (int n = 0; n < 4; ++n)
        acc[m][n] = __builtin_amdgcn_mfma_f32_16x16x32_bf16(af[m], bfr[n], acc[m][n], 0, 0, 0);
  };

  stage(0);
  __syncthreads();
  int cur = 0;
  const int NT = K / 32;
  for (int t = 0; t < NT - 1; ++t) {
    stage(cur ^ 1);          // issue next-tile loads (overlap with compute)
    compute(cur);
    __syncthreads();         // compiler drains vmcnt before barrier -> next buf ready
    cur ^= 1;
  }
  compute(cur);

  // ---- epilogue: LDS-staged coalesced bf16 C writes, two 128-row halves ----
  const int jr = (l >> 4) * 4;
#pragma unroll
  for (int h = 0; h < 2; ++h) {
    __syncthreads();
    if (wm == h) {
#pragma unroll
      for (int m = 0; m < 8; ++m)
#pragma unroll
        for (int n = 0; n < 4; ++n)
#pragma unroll
          for (int j = 0; j < 4; ++j)
            lds[(m * 16 + jr + j) * 256 + wn * 64 + n * 16 + lr] = f2b(acc[m][n][j]);
    }
    __syncthreads();
#pragma unroll
    for (int i = 0; i < 8; ++i) {
      int g = tid + i * 512;                       // 4096 granules of 16B
      int r = g >> 5, cg = g & 31;
      *reinterpret_cast<u16x8*>(C + (size_t)(bm0 + h * 128 + r) * N + bn0 + cg * 8) =
          *reinterpret_cast<const u16x8*>(lds + g * 8);
    }
  }
}

// ---------------- hm GEMV: one wave per (b,d) output ----------------
// hm[b][d] = (1/S) * sum_e xsum[b][e] * Wt1[d][e]
__global__ __launch_bounds__(256) void hm_gemv(const float* __restrict__ xsum,
                                               const u16* __restrict__ Wt1,
                                               float* __restrict__ hm) {
  const int gw = blockIdx.x * 4 + (threadIdx.x >> 6);   // 0..8191
  const int b = gw >> 10, d = gw & 1023;
  const int lane = threadIdx.x & 63;
  const u16* wr = Wt1 + (size_t)d * D_ + lane * 16;
  const float* xs = xsum + b * D_ + lane * 16;
  u16x8 w0 = *reinterpret_cast<const u16x8*>(wr);
  u16x8 w1 = *reinterpret_cast<const u16x8*>(wr + 8);
  float4 x0 = reinterpret_cast<const float4*>(xs)[0];
  float4 x1 = reinterpret_cast<const float4*>(xs)[1];
  float4 x2 = reinterpret_cast<const float4*>(xs)[2];
  float4 x3 = reinterpret_cast<const float4*>(xs)[3];
  float s = 0.f;
  const float* xf = (const float*)&x0;
#pragma unroll
  for (int k = 0; k < 8; ++k) s += xf[k] * b2f(w0[k]);          // x0,x1
  const float* xg = (const float*)&x2;
#pragma unroll
  for (int k = 0; k < 8; ++k) s += xg[k] * b2f(w1[k]);          // x2,x3
  (void)x1; (void)x3;
#pragma unroll
  for (int off = 32; off; off >>= 1) s += __shfl_xor(s, off);
  if (lane == 0) hm[gw] = s * (1.0f / S_);
}

// ---------------- coef tail: pm / normalize / dp / MLP (one block per b) ----------------
__global__ __launch_bounds__(256) void coef2_kernel(const float* __restrict__ hm,
                                                    const float* __restrict__ Wp,
                                                    const float* __restrict__ bp,
                                                    const float* __restrict__ w1,
                                                    const float* __restrict__ b1,
                                                    const float* __restrict__ w2,
                                                    const float* __restrict__ b2,
                                                    float* __restrict__ coef) {
  __shared__ float hm_s[D_];
  __shared__ float pm_s[H_ * P_];
  const int b = blockIdx.x, t = threadIdx.x;
#pragma unroll
  for (int q = 0; q < 4; ++q) hm_s[t * 4 + q] = hm[b * D_ + t * 4 + q];
  __syncthreads();
  {
    const int h = t >> 5, p = t & 31;
    float a = bp[h * P_ + p];
    const float* wp = Wp + (size_t)(h * P_ + p) * HD_;
#pragma unroll 4
    for (int e = 0; e < HD_; ++e) a += hm_s[h * HD_ + e] * wp[e];
    pm_s[t] = tanhf(a);
  }
  __syncthreads();
  if (t < 8) {
    float ss = 0.f;
    for (int p = 0; p < P_; ++p) { float v = pm_s[t * P_ + p]; ss += v * v; }
    float inv = 1.0f / fmaxf(sqrtf(ss), 1e-12f);
    for (int p = 0; p < P_; ++p) pm_s[t * P_ + p] *= inv;
  }
  __syncthreads();
  if (t < 64) {
    const int i = t >> 3, j = t & 7;
    float dp = 0.f;
    for (int p = 0; p < P_; ++p)
      dp += pm_s[i * P_ + p] * pm_s[j * P_ + p];
    float acc = b2[0];
#pragma unroll
    for (int k = 0; k < 16; ++k) {
      float z = dp * w1[k] + b1[k];
      float g = 0.5f * z * (1.0f + erff(z * 0.70710678118654752f));
      acc += g * w2[k];
    }
    float sp = (acc > 20.f) ? acc : log1pf(expf(acc));
    coef[b * 64 + t] = (i == j) ? 0.f : 0.1f / (1.0f + sp);
  }
}

// ---------------- head mixing: mixed = heads + scale(s) * coef x heads ----------------
__global__ __launch_bounds__(256) void mix_kernel(const u16* __restrict__ heads,
                                                  const float* __restrict__ coef,
                                                  u16* __restrict__ mixed) {
  __shared__ float row[D_];
  __shared__ float cf[64];
  const int r = blockIdx.x;
  const int b = r >> 11, s = r & 2047;
  const int t = threadIdx.x;
  if (t < 64) cf[t] = coef[b * 64 + t];
  const u16* hp = heads + (size_t)r * D_;
  ushort4 hv = reinterpret_cast<const ushort4*>(hp)[t];
#pragma unroll
  for (int q = 0; q < 4; ++q) row[t * 4 + q] = b2f(((u16*)&hv)[q]);
  __syncthreads();
  const float scale = (float)(s + 1) * (1.0f / S_);
  const int d0 = t * 4;
  const int h = d0 >> 7;
  float ch[8];
#pragma unroll
  for (int j = 0; j < 8; ++j) ch[j] = cf[h * 8 + j];
  ushort4 o;
#pragma unroll
  for (int q = 0; q < 4; ++q) {
    int d = d0 + q, e = d & 127;
    float tr = 0.f;
#pragma unroll
    for (int j = 0; j < 8; ++j) tr += ch[j] * row[j * 128 + e];
    ((u16*)&o)[q] = f2b(row[d] + scale * tr);
  }
  reinterpret_cast<ushort4*>(mixed + (size_t)r * D_)[t] = o;
}

// ---------------- bias + residual + LayerNorm ----------------
__global__ __launch_bounds__(256) void ln_kernel(const u16* __restrict__ ypre,
                                                 const float* __restrict__ x,
                                                 const float* __restrict__ bo,
                                                 const float* __restrict__ g,
                                                 const float* __restrict__ be,
                                                 float* __restrict__ out) {
  const int r = blockIdx.x, t = threadIdx.x;
  const u16* yp = ypre + (size_t)r * D_;
  const float* xp = x + (size_t)r * D_;
  const int d0 = t * 4;
  float4 xv = reinterpret_cast<const float4*>(xp)[t];
  ushort4 yv = reinterpret_cast<const ushort4*>(yp)[t];
  float v[4];
  float s = 0.f, ss = 0.f;
#pragma unroll
  for (int q = 0; q < 4; ++q) {
    float y = b2f(((u16*)&yv)[q]) + bo[d0 + q] + ((const float*)&xv)[q];
    v[q] = y; s += y; ss += y * y;
  }
#pragma unroll
  for (int off = 32; off; off >>= 1) {
    s += __shfl_xor(s, off);
    ss += __shfl_xor(ss, off);
  }
  __shared__ float rs[4], rss[4];
  int w = t >> 6;
  if ((t & 63) == 0) { rs[w] = s; rss[w] = ss; }
  __syncthreads();
  s = rs[0] + rs[1] + rs[2] + rs[3];
  ss = rss[0] + rss[1] + rss[2] + rss[3];
  float mu = s * (1.0f / D_);
  float var = ss * (1.0f / D_) - mu * mu;
  float rstd = rsqrtf(var + 1e-5f);
  float4 ov;
#pragma unroll
  for (int q = 0; q < 4; ++q)
    ((float*)&ov)[q] = (v[q] - mu) * rstd * g[d0 + q] + be[d0 + q];
  reinterpret_cast<float4*>(out + (size_t)r * D_)[t] = ov;
}

extern "C" void kernel_launch(void* const* d_in, const int* in_sizes, int n_in,
                              void* d_out, int out_size, void* d_ws, size_t ws_size,
                              hipStream_t stream) {
  (void)in_sizes; (void)n_in; (void)out_size; (void)ws_size;
  const float* x     = (const float*)d_in[0];
  const float* Wproj = (const float*)d_in[1];
  const float* freqs = (const float*)d_in[2];
  const float* Wp    = (const float*)d_in[3];
  const float* bp    = (const float*)d_in[4];
  const float* w1    = (const float*)d_in[5];
  const float* b1    = (const float*)d_in[6];
  const float* w2    = (const float*)d_in[7];
  const float* b2    = (const float*)d_in[8];
  const float* Wo    = (const float*)d_in[9];
  const float* bo    = (const float*)d_in[10];
  const float* ln_g  = (const float*)d_in[11];
  const float* ln_b  = (const float*)d_in[12];
  float* out = (float*)d_out;

  char* ws = (char*)d_ws;
  u16*   xbf   = (u16*)ws;                         // 33.55 MB ; later: mixed
  u16*   heads = (u16*)(ws + 33554432);            // 33.55 MB ; later: y_pre (bf16)
  u16*   Wt1   = (u16*)(ws + 67108864);            // 2 MB
  u16*   Wob   = (u16*)(ws + 69206016);            // 2 MB
  float* xsum  = (float*)(ws + 71303168);          // 32 KB
  float* hm    = (float*)(ws + 71335936);          // 32 KB
  float* coef  = (float*)(ws + 71368704);          // 2 KB

  hipMemsetAsync(xsum, 0, B_ * D_ * sizeof(float), stream);

  cvt_x_kernel<<<512, 256, 0, stream>>>(x, xbf, xsum);
  cvt_w_kernel<<<1024, 256, 0, stream>>>(Wproj, freqs, Wo, Wt1, Wob);

  hm_gemv<<<2048, 256, 0, stream>>>(xsum, Wt1, hm);
  coef2_kernel<<<8, 256, 0, stream>>>(hm, Wp, bp, w1, b1, w2, b2, coef);

  dim3 g1(BS_ / 256, D_ / 256);   // (64, 4) = 256 blocks, 1/CU
  gemm256<<<g1, 512, 0, stream>>>(xbf, Wt1, heads, BS_, D_, D_);

  mix_kernel<<<BS_, 256, 0, stream>>>(heads, coef, xbf /* mixed (aliases xbf) */);

  gemm256<<<g1, 512, 0, stream>>>(xbf, Wob, heads /* y_pre (aliases heads) */, BS_, D_, D_);

  ln_kernel<<<BS_, 256, 0, stream>>>(heads, x, bo, ln_g, ln_b, out);
}

// Round 5
// 267.502 us; speedup vs baseline: 1.3711x; 1.0104x over previous
//
#include <hip/hip_runtime.h>
#include <hip/hip_bf16.h>

#define B_  8
#define S_  2048
#define D_  1024
#define H_  8
#define HD_ 128
#define P_  32
#define BS_ (B_*S_)
#define PI_F 3.14159265358979323846f

typedef unsigned short u16;
typedef unsigned int u32;
typedef __attribute__((ext_vector_type(4))) float  f32x4;
typedef __attribute__((ext_vector_type(8))) __bf16 bf16x8;
typedef __attribute__((ext_vector_type(8))) unsigned short u16x8;

__device__ __forceinline__ u16 f2b(float f) {
  __hip_bfloat16 h = __float2bfloat16(f);
  return __builtin_bit_cast(u16, h);
}
__device__ __forceinline__ float b2f(u16 b) {
  return __bfloat162float(__builtin_bit_cast(__hip_bfloat16, b));
}

__device__ __forceinline__ void gload_lds16(const void* g, void* l) {
  auto gp = (const __attribute__((address_space(1))) unsigned int*)g;
  auto lp = (__attribute__((address_space(3))) unsigned int*)l;
  __builtin_amdgcn_global_load_lds(gp, lp, 16, 0, 0);
}

#define FENCE() asm volatile("" ::: "memory")
#define BAR() do { FENCE(); __builtin_amdgcn_sched_barrier(0); \
                   __builtin_amdgcn_s_barrier(); \
                   __builtin_amdgcn_sched_barrier(0); FENCE(); } while (0)
#define LGKM0() do { asm volatile("s_waitcnt lgkmcnt(0)" ::: "memory"); \
                     __builtin_amdgcn_sched_barrier(0); } while (0)
#define VMC(N) do { asm volatile("s_waitcnt vmcnt(" #N ")" ::: "memory"); \
                    __builtin_amdgcn_sched_barrier(0); } while (0)

// ---------------- x -> bf16, fused per-batch column sums ----------------
__global__ __launch_bounds__(256) void cvt_x_kernel(const float* __restrict__ x,
                                                    u16* __restrict__ xb,
                                                    float* __restrict__ xsum) {
  const int r0 = blockIdx.x * 32;           // 512 blocks, 32 rows each
  const int b = r0 >> 11;
  const int c = threadIdx.x * 4;
  float s0 = 0.f, s1 = 0.f, s2 = 0.f, s3 = 0.f;
#pragma unroll 4
  for (int i = 0; i < 32; ++i) {
    const float4 v = *reinterpret_cast<const float4*>(x + (size_t)(r0 + i) * D_ + c);
    ushort4 o;
    o.x = f2b(v.x); o.y = f2b(v.y); o.z = f2b(v.z); o.w = f2b(v.w);
    *reinterpret_cast<ushort4*>(xb + (size_t)(r0 + i) * D_ + c) = o;
    s0 += v.x; s1 += v.y; s2 += v.z; s3 += v.w;
  }
  atomicAdd(&xsum[b * D_ + c + 0], s0);
  atomicAdd(&xsum[b * D_ + c + 1], s1);
  atomicAdd(&xsum[b * D_ + c + 2], s2);
  atomicAdd(&xsum[b * D_ + c + 3], s3);
}

// ---------------- weights -> bf16 (fold cos(pi*f) into W_proj) ----------------
__global__ __launch_bounds__(256) void cvt_w_kernel(const float* __restrict__ Wproj,
                                                    const float* __restrict__ freqs,
                                                    const float* __restrict__ Wo,
                                                    u16* __restrict__ Wt1,
                                                    u16* __restrict__ Wob) {
  int i = blockIdx.x * blockDim.x + threadIdx.x;
  const int total = D_ * D_;
  for (; i < total; i += gridDim.x * blockDim.x) {
    int n = i >> 10;
    float c = cosf(PI_F * freqs[n]);
    Wt1[i] = f2b(Wproj[i] * c);
    Wob[i] = f2b(Wo[i]);
  }
}

// ---------------- bf16 GEMM  C(MxN) = A(MxK) * B(NxK)^T, bf16 out ----------------
// 256x256 tile, BK=64, 8 waves (2Mx4N), 8-phase schedule, counted vmcnt (T3+T4),
// setprio (T5), granule XOR swizzle (T2). LDS 128 KiB dynamic.
// Region lifetimes (derived): A-h0/h1 last read ph2; B-h0/h1 last read ph1.
// Stage rule: phase p may stage regions last-read in phase <= p-1.
//   ph0: B1(u+1) -> buf^1 (last read 2 tiles ago)      [2 loads]
//   ph1: (none)
//   ph2: B0(u+2) -> buf   (B last read ph1)            [2 loads]
//   ph3: A0(u+2), A1(u+2) -> buf (A last read ph2)     [4 loads]
// Boundary wait: outstanding after B1(u+1) = 6 -> vmcnt(6).
__global__ __launch_bounds__(512, 2) void gemm8p(const u16* __restrict__ A,
                                                 const u16* __restrict__ Bm,
                                                 u16* __restrict__ C,
                                                 int M, int N, int K) {
  extern __shared__ __align__(16) u16 smem[];     // 131072 bytes
  const int tid = threadIdx.x;
  const int l = tid & 63;
  const int wid = tid >> 6;
  const int wm = wid >> 2, wn = wid & 3;          // 2 x 4 wave grid
  const int lr = l & 15, lg = l >> 4;
  const int bm0 = blockIdx.x * 256, bn0 = blockIdx.y * 256;

  // staging: thread -> (row-in-half = tid>>3, phys granule = tid&7)
  const int srow = tid >> 3;
  const int scol = ((tid & 7) ^ (srow & 7)) * 8;  // pre-swizzled global source

  f32x4 acc[8][4] = {};
  bf16x8 af[4][2], b0[2][2], b1[2][2];

  u16* const As = smem;                 // + buf*16384 u16
  u16* const Bs = smem + 32768;

  auto stageA = [&](int half, int kt, int buf) {
    const u16* src = A + (size_t)(bm0 + half * 128 + srow) * K + kt * 64 + scol;
    u16* dst = As + buf * 16384 + half * 8192 + tid * 8;
    gload_lds16(src, dst);
    gload_lds16(src + (size_t)64 * K, dst + 4096);
  };
  auto stageB = [&](int half, int kt, int buf) {
    const u16* src = Bm + (size_t)(bn0 + half * 128 + srow) * K + kt * 64 + scol;
    u16* dst = Bs + buf * 16384 + half * 8192 + tid * 8;
    gload_lds16(src, dst);
    gload_lds16(src + (size_t)64 * K, dst + 4096);
  };
  auto readA = [&](int buf, int mh) {
#pragma unroll
    for (int mi = 0; mi < 4; ++mi)
#pragma unroll
      for (int kk = 0; kk < 2; ++kk) {
        int r = wm * 128 + mh * 64 + mi * 16 + lr;
        int g = (kk * 4 + lg) ^ (lr & 7);
        af[mi][kk] = *reinterpret_cast<const bf16x8*>(As + buf * 16384 + r * 64 + g * 8);
      }
  };
  auto readB = [&](bf16x8 (&bb)[2][2], int buf, int nh) {
#pragma unroll
    for (int ni = 0; ni < 2; ++ni)
#pragma unroll
      for (int kk = 0; kk < 2; ++kk) {
        int r = wn * 64 + (nh * 2 + ni) * 16 + lr;
        int g = (kk * 4 + lg) ^ (lr & 7);
        bb[ni][kk] = *reinterpret_cast<const bf16x8*>(Bs + buf * 16384 + r * 64 + g * 8);
      }
  };
  auto mmaq = [&](int mh, int nh, bf16x8 (&bb)[2][2]) {
    __builtin_amdgcn_s_setprio(1);
#pragma unroll
    for (int mi = 0; mi < 4; ++mi)
#pragma unroll
      for (int ni = 0; ni < 2; ++ni)
#pragma unroll
        for (int kk = 0; kk < 2; ++kk)
          acc[mh * 4 + mi][nh * 2 + ni] = __builtin_amdgcn_mfma_f32_16x16x32_bf16(
              af[mi][kk], bb[ni][kk], acc[mh * 4 + mi][nh * 2 + ni], 0, 0, 0);
    __builtin_amdgcn_s_setprio(0);
  };

  const int NT = K >> 6;                // 16

  // prologue: tile0 complete + tile1 {A0,B0,A1}  (14 loads; keep 6 newest in flight)
  stageA(0, 0, 0); stageB(0, 0, 0); stageA(1, 0, 0); stageB(1, 0, 0);
  stageA(0, 1, 1); stageB(0, 1, 1); stageA(1, 1, 1);
  VMC(6); BAR();

  auto tile = [&](int u, int buf) {
    // ph0: quadrant (mh0,nh0); stage B1(u+1) into the OTHER buffer
    readA(buf, 0); readB(b0, buf, 0);
    if (u + 1 < NT) stageB(1, u + 1, buf ^ 1);
    BAR(); LGKM0();
    mmaq(0, 0, b0);
    BAR();
    // ph1: (mh0,nh1); no staging (B-h0 still being read this phase)
    readB(b1, buf, 1);
    BAR(); LGKM0();
    mmaq(0, 1, b1);
    BAR();
    // ph2: (mh1,nh0); stage B0(u+2) (B-h0 last read ph1)
    readA(buf, 1);
    if (u + 2 < NT) stageB(0, u + 2, buf);
    BAR(); LGKM0();
    mmaq(1, 0, b0);
    BAR();
    // ph3: (mh1,nh1); stage A0+A1(u+2) (A last read ph2); boundary wait
    if (u + 2 < NT) { stageA(0, u + 2, buf); stageA(1, u + 2, buf); }
    BAR(); LGKM0();
    mmaq(1, 1, b1);
    if (u + 1 < NT) {
      if (u + 2 < NT) { VMC(6); } else { VMC(0); }
    }
    BAR();
  };

  for (int u = 0; u < NT; u += 2) {
    tile(u, 0);
    tile(u + 1, 1);
  }

  // ---- epilogue: LDS-staged coalesced bf16 C writes, two 128-row halves ----
  const int jr = (l >> 4) * 4;
#pragma unroll
  for (int h = 0; h < 2; ++h) {
    __syncthreads();
    if (wm == h) {
#pragma unroll
      for (int m = 0; m < 8; ++m)
#pragma unroll
        for (int n = 0; n < 4; ++n)
#pragma unroll
          for (int j = 0; j < 4; ++j)
            smem[(m * 16 + jr + j) * 256 + wn * 64 + n * 16 + lr] = f2b(acc[m][n][j]);
    }
    __syncthreads();
#pragma unroll
    for (int i = 0; i < 8; ++i) {
      int g = tid + i * 512;                       // 4096 granules of 16B
      int r = g >> 5, cg = g & 31;
      *reinterpret_cast<u16x8*>(C + (size_t)(bm0 + h * 128 + r) * N + bn0 + cg * 8) =
          *reinterpret_cast<const u16x8*>(smem + g * 8);
    }
  }
}

// ---------------- hm GEMV: one wave per (b,d) output ----------------
__global__ __launch_bounds__(256) void hm_gemv(const float* __restrict__ xsum,
                                               const u16* __restrict__ Wt1,
                                               float* __restrict__ hm) {
  const int gw = blockIdx.x * 4 + (threadIdx.x >> 6);   // 0..8191
  const int b = gw >> 10, d = gw & 1023;
  const int lane = threadIdx.x & 63;
  const u16* wr = Wt1 + (size_t)d * D_ + lane * 16;
  const float* xs = xsum + b * D_ + lane * 16;
  u16x8 w0 = *reinterpret_cast<const u16x8*>(wr);
  u16x8 w1 = *reinterpret_cast<const u16x8*>(wr + 8);
  float4 x0 = reinterpret_cast<const float4*>(xs)[0];
  float4 x1 = reinterpret_cast<const float4*>(xs)[1];
  float4 x2 = reinterpret_cast<const float4*>(xs)[2];
  float4 x3 = reinterpret_cast<const float4*>(xs)[3];
  float s = 0.f;
  const float* xf = (const float*)&x0;
#pragma unroll
  for (int k = 0; k < 8; ++k) s += xf[k] * b2f(w0[k]);
  const float* xg = (const float*)&x2;
#pragma unroll
  for (int k = 0; k < 8; ++k) s += xg[k] * b2f(w1[k]);
  (void)x1; (void)x3;
#pragma unroll
  for (int off = 32; off; off >>= 1) s += __shfl_xor(s, off);
  if (lane == 0) hm[gw] = s * (1.0f / S_);
}

// ---------------- coef tail: pm / normalize / dp / MLP (one block per b) ----------------
__global__ __launch_bounds__(256) void coef2_kernel(const float* __restrict__ hm,
                                                    const float* __restrict__ Wp,
                                                    const float* __restrict__ bp,
                                                    const float* __restrict__ w1,
                                                    const float* __restrict__ b1,
                                                    const float* __restrict__ w2,
                                                    const float* __restrict__ b2,
                                                    float* __restrict__ coef) {
  __shared__ float hm_s[D_];
  __shared__ float pm_s[H_ * P_];
  const int b = blockIdx.x, t = threadIdx.x;
#pragma unroll
  for (int q = 0; q < 4; ++q) hm_s[t * 4 + q] = hm[b * D_ + t * 4 + q];
  __syncthreads();
  {
    const int h = t >> 5, p = t & 31;
    float a = bp[h * P_ + p];
    const float* wp = Wp + (size_t)(h * P_ + p) * HD_;
#pragma unroll 4
    for (int e = 0; e < HD_; ++e) a += hm_s[h * HD_ + e] * wp[e];
    pm_s[t] = tanhf(a);
  }
  __syncthreads();
  if (t < 8) {
    float ss = 0.f;
    for (int p = 0; p < P_; ++p) { float v = pm_s[t * P_ + p]; ss += v * v; }
    float inv = 1.0f / fmaxf(sqrtf(ss), 1e-12f);
    for (int p = 0; p < P_; ++p) pm_s[t * P_ + p] *= inv;
  }
  __syncthreads();
  if (t < 64) {
    const int i = t >> 3, j = t & 7;
    float dp = 0.f;
    for (int p = 0; p < P_; ++p)
      dp += pm_s[i * P_ + p] * pm_s[j * P_ + p];
    float acc = b2[0];
#pragma unroll
    for (int k = 0; k < 16; ++k) {
      float z = dp * w1[k] + b1[k];
      float g = 0.5f * z * (1.0f + erff(z * 0.70710678118654752f));
      acc += g * w2[k];
    }
    float sp = (acc > 20.f) ? acc : log1pf(expf(acc));
    coef[b * 64 + t] = (i == j) ? 0.f : 0.1f / (1.0f + sp);
  }
}

// ---------------- head mixing (register version): one wave per row ----------------
// lane t owns e-pair {2t,2t+1} across all 8 heads (64 lanes * 2 * 8 = 1024 elems).
__global__ __launch_bounds__(256) void mix_kernel(const u16* __restrict__ heads,
                                                  const float* __restrict__ coef,
                                                  u16* __restrict__ mixed) {
  __shared__ float cfs[64];
  const int r = blockIdx.x * 4 + (threadIdx.x >> 6);  // 4 rows/block, 1 wave each
  const int b = blockIdx.x >> 9;                      // 512 blocks per batch
  const int s = r & 2047;
  const int t = threadIdx.x & 63;
  if (threadIdx.x < 64) cfs[threadIdx.x] = coef[b * 64 + threadIdx.x];
  __syncthreads();
  const u16* hp = heads + (size_t)r * D_ + 2 * t;
  float hx[8], hy[8];
#pragma unroll
  for (int j = 0; j < 8; ++j) {
    u32 v = *reinterpret_cast<const u32*>(hp + j * 128);
    hx[j] = b2f((u16)(v & 0xffff));
    hy[j] = b2f((u16)(v >> 16));
  }
  const float scale = (float)(s + 1) * (1.0f / S_);
  u16* op = mixed + (size_t)r * D_ + 2 * t;
#pragma unroll
  for (int i = 0; i < 8; ++i) {
    float tx = 0.f, ty = 0.f;
#pragma unroll
    for (int j = 0; j < 8; ++j) {
      float c = cfs[i * 8 + j];
      tx += c * hx[j]; ty += c * hy[j];
    }
    u32 o = (u32)f2b(hx[i] + scale * tx) | ((u32)f2b(hy[i] + scale * ty) << 16);
    *reinterpret_cast<u32*>(op + i * 128) = o;
  }
}

// ---------------- bias + residual + LayerNorm ----------------
__global__ __launch_bounds__(256) void ln_kernel(const u16* __restrict__ ypre,
                                                 const float* __restrict__ x,
                                                 const float* __restrict__ bo,
                                                 const float* __restrict__ g,
                                                 const float* __restrict__ be,
                                                 float* __restrict__ out) {
  const int r = blockIdx.x, t = threadIdx.x;
  const u16* yp = ypre + (size_t)r * D_;
  const float* xp = x + (size_t)r * D_;
  const int d0 = t * 4;
  float4 xv = reinterpret_cast<const float4*>(xp)[t];
  ushort4 yv = reinterpret_cast<const ushort4*>(yp)[t];
  float v[4];
  float s = 0.f, ss = 0.f;
#pragma unroll
  for (int q = 0; q < 4; ++q) {
    float y = b2f(((u16*)&yv)[q]) + bo[d0 + q] + ((const float*)&xv)[q];
    v[q] = y; s += y; ss += y * y;
  }
#pragma unroll
  for (int off = 32; off; off >>= 1) {
    s += __shfl_xor(s, off);
    ss += __shfl_xor(ss, off);
  }
  __shared__ float rs[4], rss[4];
  int w = t >> 6;
  if ((t & 63) == 0) { rs[w] = s; rss[w] = ss; }
  __syncthreads();
  s = rs[0] + rs[1] + rs[2] + rs[3];
  ss = rss[0] + rss[1] + rss[2] + rss[3];
  float mu = s * (1.0f / D_);
  float var = ss * (1.0f / D_) - mu * mu;
  float rstd = rsqrtf(var + 1e-5f);
  float4 ov;
#pragma unroll
  for (int q = 0; q < 4; ++q)
    ((float*)&ov)[q] = (v[q] - mu) * rstd * g[d0 + q] + be[d0 + q];
  reinterpret_cast<float4*>(out + (size_t)r * D_)[t] = ov;
}

extern "C" void kernel_launch(void* const* d_in, const int* in_sizes, int n_in,
                              void* d_out, int out_size, void* d_ws, size_t ws_size,
                              hipStream_t stream) {
  (void)in_sizes; (void)n_in; (void)out_size; (void)ws_size;
  const float* x     = (const float*)d_in[0];
  const float* Wproj = (const float*)d_in[1];
  const float* freqs = (const float*)d_in[2];
  const float* Wp    = (const float*)d_in[3];
  const float* bp    = (const float*)d_in[4];
  const float* w1    = (const float*)d_in[5];
  const float* b1    = (const float*)d_in[6];
  const float* w2    = (const float*)d_in[7];
  const float* b2    = (const float*)d_in[8];
  const float* Wo    = (const float*)d_in[9];
  const float* bo    = (const float*)d_in[10];
  const float* ln_g  = (const float*)d_in[11];
  const float* ln_b  = (const float*)d_in[12];
  float* out = (float*)d_out;

  char* ws = (char*)d_ws;
  u16*   xbf   = (u16*)ws;                         // 33.55 MB ; later: mixed
  u16*   heads = (u16*)(ws + 33554432);            // 33.55 MB ; later: y_pre (bf16)
  u16*   Wt1   = (u16*)(ws + 67108864);            // 2 MB
  u16*   Wob   = (u16*)(ws + 69206016);            // 2 MB
  float* xsum  = (float*)(ws + 71303168);          // 32 KB
  float* hm    = (float*)(ws + 71335936);          // 32 KB
  float* coef  = (float*)(ws + 71368704);          // 2 KB

  hipFuncSetAttribute((const void*)gemm8p,
                      hipFuncAttributeMaxDynamicSharedMemorySize, 131072);

  hipMemsetAsync(xsum, 0, B_ * D_ * sizeof(float), stream);

  cvt_x_kernel<<<512, 256, 0, stream>>>(x, xbf, xsum);
  cvt_w_kernel<<<1024, 256, 0, stream>>>(Wproj, freqs, Wo, Wt1, Wob);

  hm_gemv<<<2048, 256, 0, stream>>>(xsum, Wt1, hm);
  coef2_kernel<<<8, 256, 0, stream>>>(hm, Wp, bp, w1, b1, w2, b2, coef);

  dim3 g1(BS_ / 256, D_ / 256);   // (64, 4) = 256 blocks, 1/CU
  gemm8p<<<g1, 512, 131072, stream>>>(xbf, Wt1, heads, BS_, D_, D_);

  mix_kernel<<<BS_ / 4, 256, 0, stream>>>(heads, coef, xbf /* mixed */);

  gemm8p<<<g1, 512, 131072, stream>>>(xbf, Wob, heads /* y_pre */, BS_, D_, D_);

  ln_kernel<<<BS_, 256, 0, stream>>>(heads, x, bo, ln_g, ln_b, out);
}